// Round 3
// baseline (1086.486 us; speedup 1.0000x reference)
//
#include <hip/hip_runtime.h>
#include <hip/hip_cooperative_groups.h>
#include <math.h>

namespace cg = cooperative_groups;

#define BB 8
#define FF 256
#define SS 1024
#define KK 16
#define ITERS 5

typedef unsigned long long ull;

// ---------- wm stage 1: partial column sums of w ----------
#define ICH 8
__global__ void wm_part_kernel(const float* __restrict__ w, float* __restrict__ part) {
    int j = blockIdx.x * 256 + threadIdx.x;
    int ic = blockIdx.y, b = blockIdx.z;
    const float* wp = w + (size_t)b * SS * SS + (size_t)ic * (SS / ICH) * SS + j;
    float s = 0.f;
#pragma unroll 16
    for (int i = 0; i < SS / ICH; ++i) s += wp[(size_t)i * SS];
    part[((size_t)ic * BB + b) * SS + j] = s;
}

// ---------- d[b][i][j] = sum_f |x[b][f][i] - x[b][f][j]| ----------
// R10: 64x64 wave-private tiles, 8x8 acc per lane. Halves LDS bytes/elem
// and staging traffic vs 32x32/4x4; 1024 VALU insts per chunk hide the
// depth-1 prefetch. VALU floor ~29us. f ascending -> d bitwise identical.
// __launch_bounds__(128,2): 256-VGPR cap, acc=64 + ~40 misc, no spill.
#define FCD 8
#define TS 64
#define NT (SS / TS)
__device__ __forceinline__ void async_copy16(const float* g, const float* s) {
    __builtin_amdgcn_global_load_lds((const __attribute__((address_space(1))) void*)g,
                                     (__attribute__((address_space(3))) void*)s, 16, 0, 0);
}

__global__ __launch_bounds__(128, 2) void dist_kernel(const float* __restrict__ x,
                                                      float* __restrict__ d) {
    __shared__ float smem[4096];   // per wave (2048): buf0 [A 512|B 512] buf1 [A|B]
    int tid = threadIdx.x;
    int wave = tid >> 6, lane = tid & 63;
    int b = blockIdx.y;
    int w = blockIdx.x * 2 + wave;      // 0..135 triangular tile id (64x64 tiles)
    int it = 0, rem = w;
    while (rem >= NT - it) { rem -= NT - it; ++it; }
    int jt = it + rem;
    int i0 = it * TS, j0 = jt * TS;
    const float* xb = x + (size_t)b * FF * SS;
    float* db = d + (size_t)b * SS * SS;
    float* wbase = smem + wave * 2048;
    int ly = lane >> 3, lx = lane & 7;            // 8x8 lane grid, 8x8 elems each
    int sFl = lane >> 4, sTk = (lane & 15) * 4;   // staging: 4 f-rows x 64 tok/inst

    float acc[8][8] = {};

    auto stage = [&](int c, int h) {
        float* A = wbase + h * 1024;
        const float* base = xb + ((size_t)c * FCD + sFl) * SS;
        async_copy16(base + i0 + sTk, A);                 // A f0..3 (4f x 64tok)
        async_copy16(base + 4 * SS + i0 + sTk, A + 256);  // A f4..7
        async_copy16(base + j0 + sTk, A + 512);           // B f0..3
        async_copy16(base + 4 * SS + j0 + sTk, A + 768);  // B f4..7
    };
    auto compute = [&](int h) {
        const float* A = wbase + h * 1024;
        const float* B = A + 512;
#pragma unroll
        for (int f = 0; f < FCD; ++f) {
            float4 a0 = *(const float4*)(A + f * 64 + ly * 8);
            float4 a1 = *(const float4*)(A + f * 64 + ly * 8 + 4);
            float4 b0 = *(const float4*)(B + f * 64 + lx * 8);
            float4 b1 = *(const float4*)(B + f * 64 + lx * 8 + 4);
            float av[8] = {a0.x, a0.y, a0.z, a0.w, a1.x, a1.y, a1.z, a1.w};
            float bv[8] = {b0.x, b0.y, b0.z, b0.w, b1.x, b1.y, b1.z, b1.w};
#pragma unroll
            for (int r = 0; r < 8; ++r)
#pragma unroll
                for (int c = 0; c < 8; ++c)
                    acc[r][c] += fabsf(av[r] - bv[c]);
        }
    };

    stage(0, 0);
#pragma unroll 1
    for (int k = 0; k < FF / FCD - 1; ++k) {
        // WAR: ds_reads of the buffer we are about to overwrite have retired
        asm volatile("s_waitcnt lgkmcnt(0)" ::: "memory");
        stage(k + 1, (k + 1) & 1);
        // wait only for chunk k's 4 loads; chunk k+1's 4 stay in flight
        asm volatile("s_waitcnt vmcnt(4)" ::: "memory");
        compute(k & 1);
    }
    asm volatile("s_waitcnt vmcnt(0)" ::: "memory");
    compute(1);   // chunk 31 -> buffer 1

    // direct tile: rows i0+ly*8+r, cols j0+lx*8 (+4)
#pragma unroll
    for (int r = 0; r < 8; ++r) {
        float4 v0 = make_float4(acc[r][0], acc[r][1], acc[r][2], acc[r][3]);
        float4 v1 = make_float4(acc[r][4], acc[r][5], acc[r][6], acc[r][7]);
        float* row = &db[(size_t)(i0 + ly * 8 + r) * SS + j0 + lx * 8];
        *(float4*)row = v0;
        *(float4*)(row + 4) = v1;
    }
    if (it != jt) {
        // mirror straight from registers (d bitwise symmetric)
#pragma unroll
        for (int c = 0; c < 8; ++c) {
            float4 v0 = make_float4(acc[0][c], acc[1][c], acc[2][c], acc[3][c]);
            float4 v1 = make_float4(acc[4][c], acc[5][c], acc[6][c], acc[7][c]);
            float* row = &db[(size_t)(j0 + lx * 8 + c) * SS + i0 + ly * 8];
            *(float4*)row = v0;
            *(float4*)(row + 4) = v1;
        }
    }
}

// ---------- wm finalize + topk (jax.lax.top_k) + initial assign, fused ----------
// wm > 0 strictly (means of uniform[0,1)), so float bits are order-monotonic.
__global__ __launch_bounds__(1024) void topk_assign_kernel(const float* __restrict__ part,
                                                           float* __restrict__ wm,
                                                           const float* __restrict__ d,
                                                           int* __restrict__ assign) {
    int b = blockIdx.x;
    int tid = threadIdx.x;          // == token index
    int lane = tid & 63, wv = tid >> 6;
    __shared__ ull red[16];
    __shared__ int ctr_s[KK];
    // finalize wm for this batch (same ascending-ic order as before)
    float v = 0.f;
#pragma unroll
    for (int ic = 0; ic < ICH; ++ic) v += part[((size_t)ic * BB + b) * SS + tid];
    v *= (1.0f / SS);
    wm[b * SS + tid] = v;
    // key: value-desc, tie -> smaller index (complemented idx, max-reduce)
    ull key = (((ull)__float_as_uint(v)) << 32) | (ull)(0xFFFFFFFFu - (unsigned)tid);
    for (int k = 0; k < KK; ++k) {
        ull kk = key;
#pragma unroll
        for (int off = 32; off; off >>= 1) {
            ull o = __shfl_down(kk, off, 64);
            if (o > kk) kk = o;
        }
        if (lane == 0) red[wv] = kk;
        __syncthreads();
        if (wv == 0) {
            ull k2 = (lane < 16) ? red[lane] : 0ull;
#pragma unroll
            for (int off = 8; off; off >>= 1) {
                ull o = __shfl_down(k2, off, 64);
                if (o > k2) k2 = o;
            }
            if (lane == 0) red[0] = k2;
        }
        __syncthreads();
        ull W = red[0];
        int widx = (int)(0xFFFFFFFFu - (unsigned)(W & 0xFFFFFFFFu));
        if (tid == widx) key = 0;            // remove winner
        if (tid == 0) ctr_s[k] = widx;
        __syncthreads();                      // protect red[] before next round
    }
    // initial assign: argmin_k d[ctr[k]][i] (d symmetric; coalesced over i)
    const float* db = d + (size_t)b * SS * SS;
    float bv = INFINITY;
    int bk = 0;
#pragma unroll
    for (int k = 0; k < KK; ++k) {
        float vv = db[(size_t)ctr_s[k] * SS + tid];
        if (vv < bv) { bv = vv; bk = k; }    // strict < keeps first k
    }
    assign[b * SS + tid] = bk;
}

// ---------- R12: whole k-medoids loop in ONE cooperative kernel ----------
// 512 blocks x 256 threads (b = blk>>6, ib = blk&63), 12.4 KB LDS ->
// co-resident (2 blocks/CU). Per iteration: cost phase (verbatim
// cost_kernel body -> bitwise-identical cost[]), fence+grid.sync, medoid
// argmin (same per-cluster scan, 4 waves x 4 clusters sequentially),
// new-assign via 16-lane segmented packed-key min (distinct keys -> total
// order -> topology-independent, == old 4-group hierarchical min),
// fence+grid.sync. Replaces 10 dependent launches (~110us of dispatch
// latency) with 9 grid barriers.
#define RPB 16
__global__ __launch_bounds__(256) void iter_kernel(
        const float* __restrict__ d, const float* __restrict__ wm,
        int* __restrict__ assign, float* __restrict__ cost,
        const float* __restrict__ x, float* __restrict__ out) {
    cg::grid_group grid = cg::this_grid();
    int g = blockIdx.x;
    int b = g >> 6, ib = g & 63;
    int tid = threadIdx.x;
    int lane = tid & 63, wv = tid >> 6;
    __shared__ float wmv[SS];
    __shared__ int asg[SS];
    __shared__ float cost_s[SS];
    __shared__ int ctr_s[KK];
    const float* db = d + (size_t)b * SS * SS;
    // wm constant across iterations: load once
    *(float4*)&wmv[tid * 4] = *(const float4*)&wm[b * SS + tid * 4];

    for (int itr = 0; itr < ITERS; ++itr) {
        // assign changes every iteration
        *(int4*)&asg[tid * 4] = *(const int4*)&assign[b * SS + tid * 4];
        __syncthreads();
        // ---- phase A: cost rows ib*16 + wv*4 + r (verbatim cost_kernel) ----
#pragma unroll
        for (int r = 0; r < RPB / 4; ++r) {
            int i = ib * RPB + wv * (RPB / 4) + r;
            int my = asg[i];
            const float* drow = db + (size_t)i * SS;
            float s = 0.f;
#pragma unroll
            for (int c = 0; c < SS / 256; ++c) {  // 4 sweeps of 64 lanes x float4
                int j = c * 256 + lane * 4;
                float4 dv = *(const float4*)&drow[j];
                float4 wv4 = *(const float4*)&wmv[j];
                int4 a4 = *(const int4*)&asg[j];
                s += (a4.x == my) ? dv.x * wv4.x : 0.f;
                s += (a4.y == my) ? dv.y * wv4.y : 0.f;
                s += (a4.z == my) ? dv.z * wv4.z : 0.f;
                s += (a4.w == my) ? dv.w * wv4.w : 0.f;
            }
#pragma unroll
            for (int off = 32; off; off >>= 1) s += __shfl_down(s, off, 64);
            if (lane == 0) cost[b * SS + i] = s;
        }
        __threadfence();
        grid.sync();
        // ---- phase B: medoid argmin (all blocks, redundant per batch) ----
        *(float4*)&cost_s[tid * 4] = *(const float4*)&cost[b * SS + tid * 4];
        __syncthreads();
#pragma unroll
        for (int q = 0; q < 4; ++q) {
            int k = wv + q * 4;         // wave wv: clusters wv, wv+4, wv+8, wv+12
            ull best = ~0ull;
            for (int c = 0; c < SS / 64; ++c) {
                int i = c * 64 + lane;
                if (asg[i] == k) {
                    ull key = (((ull)__float_as_uint(cost_s[i])) << 32) | (unsigned)i;
                    if (key < best) best = key;
                }
            }
#pragma unroll
            for (int off = 32; off; off >>= 1) {
                ull o = __shfl_down(best, off, 64);
                if (o < best) best = o;
            }
            if (lane == 0) ctr_s[k] = (best == ~0ull) ? 0 : (int)(best & 0xFFFFFFFFu);
        }
        __syncthreads();
        if (itr != ITERS - 1) {
            // new assign: this block's 16 tokens; 16 lanes/token (one per k)
            int tok = ib * RPB + (tid >> 4);
            int k = tid & 15;
            float vv = db[(size_t)ctr_s[k] * SS + tok];
            ull key = (((ull)__float_as_uint(vv)) << 32) | (unsigned)k;
#pragma unroll
            for (int off = 8; off; off >>= 1) {
                ull o = __shfl_down(key, off, 16);
                if (o < key) key = o;
            }
            if ((tid & 15) == 0) assign[b * SS + tok] = (int)(key & 0xFFFFFFFFu);
            __threadfence();
            grid.sync();
        } else {
            // final gather: 64 elems per block; e = ib*64+tid covers FF*KK
            if (tid < 64) {
                int e = ib * 64 + tid;
                int f = e / KK, k2 = e % KK;
                out[((size_t)b * FF + f) * KK + k2] = x[((size_t)b * FF + f) * SS + ctr_s[k2]];
            }
        }
    }
}

// ---------- fallback pair (R11 path) in case cooperative launch refuses ----------
__global__ __launch_bounds__(256) void cost_kernel(const float* __restrict__ d,
                                                   const float* __restrict__ wm,
                                                   const int* __restrict__ assign,
                                                   float* __restrict__ cost) {
    int b = blockIdx.y;
    int tid = threadIdx.x;
    int lane = tid & 63, wv = tid >> 6;
    __shared__ float wmv[SS];
    __shared__ int asg[SS];
    *(float4*)&wmv[tid * 4] = *(const float4*)&wm[b * SS + tid * 4];
    *(int4*)&asg[tid * 4] = *(const int4*)&assign[b * SS + tid * 4];
    __syncthreads();
    const float* db = d + (size_t)b * SS * SS;
#pragma unroll
    for (int r = 0; r < RPB / 4; ++r) {
        int i = blockIdx.x * RPB + wv * (RPB / 4) + r;
        int my = asg[i];
        const float* drow = db + (size_t)i * SS;
        float s = 0.f;
#pragma unroll
        for (int c = 0; c < SS / 256; ++c) {
            int j = c * 256 + lane * 4;
            float4 dv = *(const float4*)&drow[j];
            float4 wv4 = *(const float4*)&wmv[j];
            int4 a4 = *(const int4*)&asg[j];
            s += (a4.x == my) ? dv.x * wv4.x : 0.f;
            s += (a4.y == my) ? dv.y * wv4.y : 0.f;
            s += (a4.z == my) ? dv.z * wv4.z : 0.f;
            s += (a4.w == my) ? dv.w * wv4.w : 0.f;
        }
#pragma unroll
        for (int off = 32; off; off >>= 1) s += __shfl_down(s, off, 64);
        if (lane == 0) cost[b * SS + i] = s;
    }
}

__global__ __launch_bounds__(1024) void update_assign_kernel(
        const float* __restrict__ d, const float* __restrict__ cost,
        int* __restrict__ assign, const float* __restrict__ x,
        float* __restrict__ out, int last) {
    int b = blockIdx.y;
    int q = blockIdx.x;
    int tid = threadIdx.x;
    int lane = tid & 63, wv = tid >> 6;
    __shared__ float cost_s[SS];
    __shared__ int assign_s[SS];
    __shared__ int ctr_s[KK];
    __shared__ ull pk[4][256];
    cost_s[tid] = cost[b * SS + tid];
    assign_s[tid] = assign[b * SS + tid];
    __syncthreads();
    ull best = ~0ull;
    int k = wv;
    for (int c = 0; c < SS / 64; ++c) {
        int i = c * 64 + lane;
        if (assign_s[i] == k) {
            ull key = (((ull)__float_as_uint(cost_s[i])) << 32) | (unsigned)i;
            if (key < best) best = key;
        }
    }
#pragma unroll
    for (int off = 32; off; off >>= 1) {
        ull o = __shfl_down(best, off, 64);
        if (o < best) best = o;
    }
    if (lane == 0) ctr_s[k] = (best == ~0ull) ? 0 : (int)(best & 0xFFFFFFFFu);
    __syncthreads();
    const float* db = d + (size_t)b * SS * SS;
    if (!last) {
        int tok = q * 256 + (tid & 255);
        int g = tid >> 8;
        ull bk = ~0ull;
#pragma unroll
        for (int kk = 0; kk < 4; ++kk) {
            int k2 = g * 4 + kk;
            float vv = db[(size_t)ctr_s[k2] * SS + tok];
            ull key = (((ull)__float_as_uint(vv)) << 32) | (unsigned)k2;
            if (key < bk) bk = key;
        }
        pk[g][tid & 255] = bk;
        __syncthreads();
        if (tid < 256) {
            ull m = pk[0][tid];
            if (pk[1][tid] < m) m = pk[1][tid];
            if (pk[2][tid] < m) m = pk[2][tid];
            if (pk[3][tid] < m) m = pk[3][tid];
            assign[b * SS + q * 256 + tid] = (int)(m & 0xFFFFFFFFu);
        }
    } else {
        int e = q * 1024 + tid;
        int f = e / KK, k2 = e % KK;
        out[((size_t)b * FF + f) * KK + k2] = x[((size_t)b * FF + f) * SS + ctr_s[k2]];
    }
}

extern "C" void kernel_launch(void* const* d_in, const int* in_sizes, int n_in,
                              void* d_out, int out_size, void* d_ws, size_t ws_size,
                              hipStream_t stream) {
    const float* x = (const float*)d_in[0];   // [B,F,S]
    const float* w = (const float*)d_in[1];   // [B,S,S]
    float* out = (float*)d_out;               // [B,F,K]

    char* ws = (char*)d_ws;
    float* d = (float*)ws;                              // B*S*S floats = 33.55 MB
    size_t off = (size_t)BB * SS * SS * sizeof(float);
    float* wm = (float*)(ws + off);   off += (size_t)BB * SS * sizeof(float);
    int* assign = (int*)(ws + off);   off += (size_t)BB * SS * sizeof(int);
    float* cost = (float*)(ws + off); off += (size_t)BB * SS * sizeof(float);
    float* part = (float*)(ws + off); // [ICH][B][S] = 256 KB (non-aliasing:
                                      // consumed by topk AFTER dist runs)

    // dist first, wm_part second — independent data; wm_part's 256 blocks
    // backfill dist's ragged drain tail (544 blocks over 256 CUs).
    dist_kernel<<<dim3(68, BB), 128, 0, stream>>>(x, d);
    wm_part_kernel<<<dim3(SS / 256, ICH, BB), 256, 0, stream>>>(w, part);
    topk_assign_kernel<<<BB, 1024, 0, stream>>>(part, wm, d, assign);

    // R12: one cooperative launch replaces the 10-launch iteration loop.
    void* args[] = {(void*)&d, (void*)&wm, (void*)&assign, (void*)&cost,
                    (void*)&x, (void*)&out};
    hipError_t ce = hipLaunchCooperativeKernel((const void*)iter_kernel, dim3(512),
                                               dim3(256), args, 0, stream);
    if (ce != hipSuccess) {
        // fallback: measured-good R11 loop
        for (int itr = 0; itr < ITERS; ++itr) {
            cost_kernel<<<dim3(SS / RPB, BB), 256, 0, stream>>>(d, wm, assign, cost);
            update_assign_kernel<<<dim3(4, BB), 1024, 0, stream>>>(d, cost, assign, x, out,
                                                                   itr == ITERS - 1 ? 1 : 0);
        }
    }
}

// Round 4
// 282.479 us; speedup vs baseline: 3.8462x; 3.8462x over previous
//
#include <hip/hip_runtime.h>
#include <math.h>

#define BB 8
#define FF 256
#define SS 1024
#define KK 16
#define ITERS 5

typedef unsigned long long ull;

// R12 POST-MORTEM: cooperative grid.sync() fusion = 850us for the loop
// (VALUBusy 1.2%, 9 barriers ~= 94us each). Grid-wide software barriers
// are ~10x a kernel-launch boundary on MI355X. Reverted to multi-launch.

// ---------- wm stage 1: partial column sums of w ----------
#define ICH 8
__global__ void wm_part_kernel(const float* __restrict__ w, float* __restrict__ part) {
    int j = blockIdx.x * 256 + threadIdx.x;
    int ic = blockIdx.y, b = blockIdx.z;
    const float* wp = w + (size_t)b * SS * SS + (size_t)ic * (SS / ICH) * SS + j;
    float s = 0.f;
#pragma unroll 16
    for (int i = 0; i < SS / ICH; ++i) s += wp[(size_t)i * SS];
    part[((size_t)ic * BB + b) * SS + j] = s;
}

// ---------- d[b][i][j] = sum_f |x[b][f][i] - x[b][f][j]| ----------
// R10 (verified bitwise-exact in R3 run): 64x64 wave-private tiles, 8x8
// acc per lane. 1 B LDS-read/elem, 139 MB staging, 1024 VALU insts per
// chunk hide depth-1 prefetch. VALU floor ~29us.
// __launch_bounds__(128,2): 256-VGPR cap, acc=64 + ~40 misc, no spill.
#define FCD 8
#define TS 64
#define NT (SS / TS)
__device__ __forceinline__ void async_copy16(const float* g, const float* s) {
    __builtin_amdgcn_global_load_lds((const __attribute__((address_space(1))) void*)g,
                                     (__attribute__((address_space(3))) void*)s, 16, 0, 0);
}

__global__ __launch_bounds__(128, 2) void dist_kernel(const float* __restrict__ x,
                                                      float* __restrict__ d) {
    __shared__ float smem[4096];   // per wave (2048): buf0 [A 512|B 512] buf1 [A|B]
    int tid = threadIdx.x;
    int wave = tid >> 6, lane = tid & 63;
    int b = blockIdx.y;
    int w = blockIdx.x * 2 + wave;      // 0..135 triangular tile id (64x64 tiles)
    int it = 0, rem = w;
    while (rem >= NT - it) { rem -= NT - it; ++it; }
    int jt = it + rem;
    int i0 = it * TS, j0 = jt * TS;
    const float* xb = x + (size_t)b * FF * SS;
    float* db = d + (size_t)b * SS * SS;
    float* wbase = smem + wave * 2048;
    int ly = lane >> 3, lx = lane & 7;            // 8x8 lane grid, 8x8 elems each
    int sFl = lane >> 4, sTk = (lane & 15) * 4;   // staging: 4 f-rows x 64 tok/inst

    float acc[8][8] = {};

    auto stage = [&](int c, int h) {
        float* A = wbase + h * 1024;
        const float* base = xb + ((size_t)c * FCD + sFl) * SS;
        async_copy16(base + i0 + sTk, A);                 // A f0..3 (4f x 64tok)
        async_copy16(base + 4 * SS + i0 + sTk, A + 256);  // A f4..7
        async_copy16(base + j0 + sTk, A + 512);           // B f0..3
        async_copy16(base + 4 * SS + j0 + sTk, A + 768);  // B f4..7
    };
    auto compute = [&](int h) {
        const float* A = wbase + h * 1024;
        const float* B = A + 512;
#pragma unroll
        for (int f = 0; f < FCD; ++f) {
            float4 a0 = *(const float4*)(A + f * 64 + ly * 8);
            float4 a1 = *(const float4*)(A + f * 64 + ly * 8 + 4);
            float4 b0 = *(const float4*)(B + f * 64 + lx * 8);
            float4 b1 = *(const float4*)(B + f * 64 + lx * 8 + 4);
            float av[8] = {a0.x, a0.y, a0.z, a0.w, a1.x, a1.y, a1.z, a1.w};
            float bv[8] = {b0.x, b0.y, b0.z, b0.w, b1.x, b1.y, b1.z, b1.w};
#pragma unroll
            for (int r = 0; r < 8; ++r)
#pragma unroll
                for (int c = 0; c < 8; ++c)
                    acc[r][c] += fabsf(av[r] - bv[c]);
        }
    };

    stage(0, 0);
#pragma unroll 1
    for (int k = 0; k < FF / FCD - 1; ++k) {
        // WAR: ds_reads of the buffer we are about to overwrite have retired
        asm volatile("s_waitcnt lgkmcnt(0)" ::: "memory");
        stage(k + 1, (k + 1) & 1);
        // wait only for chunk k's 4 loads; chunk k+1's 4 stay in flight
        asm volatile("s_waitcnt vmcnt(4)" ::: "memory");
        compute(k & 1);
    }
    asm volatile("s_waitcnt vmcnt(0)" ::: "memory");
    compute(1);   // chunk 31 -> buffer 1

    // direct tile: rows i0+ly*8+r, cols j0+lx*8 (+4)
#pragma unroll
    for (int r = 0; r < 8; ++r) {
        float4 v0 = make_float4(acc[r][0], acc[r][1], acc[r][2], acc[r][3]);
        float4 v1 = make_float4(acc[r][4], acc[r][5], acc[r][6], acc[r][7]);
        float* row = &db[(size_t)(i0 + ly * 8 + r) * SS + j0 + lx * 8];
        *(float4*)row = v0;
        *(float4*)(row + 4) = v1;
    }
    if (it != jt) {
        // mirror straight from registers (d bitwise symmetric)
#pragma unroll
        for (int c = 0; c < 8; ++c) {
            float4 v0 = make_float4(acc[0][c], acc[1][c], acc[2][c], acc[3][c]);
            float4 v1 = make_float4(acc[4][c], acc[5][c], acc[6][c], acc[7][c]);
            float* row = &db[(size_t)(j0 + lx * 8 + c) * SS + i0 + ly * 8];
            *(float4*)row = v0;
            *(float4*)(row + 4) = v1;
        }
    }
}

// ---------- wm finalize + topk (jax.lax.top_k) + initial assign, fused ----------
// wm > 0 strictly (means of uniform[0,1)), so float bits are order-monotonic.
__global__ __launch_bounds__(1024) void topk_assign_kernel(const float* __restrict__ part,
                                                           float* __restrict__ wm,
                                                           const float* __restrict__ d,
                                                           int* __restrict__ assign) {
    int b = blockIdx.x;
    int tid = threadIdx.x;          // == token index
    int lane = tid & 63, wv = tid >> 6;
    __shared__ ull red[16];
    __shared__ int ctr_s[KK];
    // finalize wm for this batch (same ascending-ic order as before)
    float v = 0.f;
#pragma unroll
    for (int ic = 0; ic < ICH; ++ic) v += part[((size_t)ic * BB + b) * SS + tid];
    v *= (1.0f / SS);
    wm[b * SS + tid] = v;
    // key: value-desc, tie -> smaller index (complemented idx, max-reduce)
    ull key = (((ull)__float_as_uint(v)) << 32) | (ull)(0xFFFFFFFFu - (unsigned)tid);
    for (int k = 0; k < KK; ++k) {
        ull kk = key;
#pragma unroll
        for (int off = 32; off; off >>= 1) {
            ull o = __shfl_down(kk, off, 64);
            if (o > kk) kk = o;
        }
        if (lane == 0) red[wv] = kk;
        __syncthreads();
        if (wv == 0) {
            ull k2 = (lane < 16) ? red[lane] : 0ull;
#pragma unroll
            for (int off = 8; off; off >>= 1) {
                ull o = __shfl_down(k2, off, 64);
                if (o > k2) k2 = o;
            }
            if (lane == 0) red[0] = k2;
        }
        __syncthreads();
        ull W = red[0];
        int widx = (int)(0xFFFFFFFFu - (unsigned)(W & 0xFFFFFFFFu));
        if (tid == widx) key = 0;            // remove winner
        if (tid == 0) ctr_s[k] = widx;
        __syncthreads();                      // protect red[] before next round
    }
    // initial assign: argmin_k d[ctr[k]][i] (d symmetric; coalesced over i)
    const float* db = d + (size_t)b * SS * SS;
    float bv = INFINITY;
    int bk = 0;
#pragma unroll
    for (int k = 0; k < KK; ++k) {
        float vv = db[(size_t)ctr_s[k] * SS + tid];
        if (vv < bv) { bv = vv; bk = k; }    // strict < keeps first k
    }
    assign[b * SS + tid] = bk;
}

// ---------- cost[b][i] = sum_{j: assign[j]==assign[i]} d[i][j]*wm[j] ----------
// 16 rows per block: wm+assign cached in LDS once, 4 waves x 4 rows,
// barrier-free per-row wave reduction.
#define RPB 16
__global__ __launch_bounds__(256) void cost_kernel(const float* __restrict__ d,
                                                   const float* __restrict__ wm,
                                                   const int* __restrict__ assign,
                                                   float* __restrict__ cost) {
    int b = blockIdx.y;
    int tid = threadIdx.x;
    int lane = tid & 63, wv = tid >> 6;
    __shared__ float wmv[SS];
    __shared__ int asg[SS];
    *(float4*)&wmv[tid * 4] = *(const float4*)&wm[b * SS + tid * 4];
    *(int4*)&asg[tid * 4] = *(const int4*)&assign[b * SS + tid * 4];
    __syncthreads();
    const float* db = d + (size_t)b * SS * SS;
#pragma unroll
    for (int r = 0; r < RPB / 4; ++r) {
        int i = blockIdx.x * RPB + wv * (RPB / 4) + r;
        int my = asg[i];
        const float* drow = db + (size_t)i * SS;
        float s = 0.f;
#pragma unroll
        for (int c = 0; c < SS / 256; ++c) {      // 4 sweeps of 64 lanes x float4
            int j = c * 256 + lane * 4;
            float4 dv = *(const float4*)&drow[j];
            float4 wv4 = *(const float4*)&wmv[j];
            int4 a4 = *(const int4*)&asg[j];
            s += (a4.x == my) ? dv.x * wv4.x : 0.f;
            s += (a4.y == my) ? dv.y * wv4.y : 0.f;
            s += (a4.z == my) ? dv.z * wv4.z : 0.f;
            s += (a4.w == my) ? dv.w * wv4.w : 0.f;
        }
#pragma unroll
        for (int off = 32; off; off >>= 1) s += __shfl_down(s, off, 64);
        if (lane == 0) cost[b * SS + i] = s;
    }
}

// ---------- medoid update (+ next assign, or final gather), widened ----------
// grid (4, B): each block redundantly computes all K medoids (cheap 8 KB
// LDS scan), then handles a 256-token quarter of the assign (or gather).
__global__ __launch_bounds__(1024) void update_assign_kernel(
        const float* __restrict__ d, const float* __restrict__ cost,
        int* __restrict__ assign, const float* __restrict__ x,
        float* __restrict__ out, int last) {
    int b = blockIdx.y;
    int q = blockIdx.x;             // quarter 0..3
    int tid = threadIdx.x;
    int lane = tid & 63, wv = tid >> 6;
    __shared__ float cost_s[SS];
    __shared__ int assign_s[SS];
    __shared__ int ctr_s[KK];
    __shared__ ull pk[4][256];
    cost_s[tid] = cost[b * SS + tid];
    assign_s[tid] = assign[b * SS + tid];
    __syncthreads();
    // per-cluster argmin: wave wv handles cluster k=wv.
    // cost >= 0 finite, so float bits are order-monotonic.
    ull best = ~0ull;
    int k = wv;   // 16 waves, 16 clusters
    for (int c = 0; c < SS / 64; ++c) {
        int i = c * 64 + lane;
        if (assign_s[i] == k) {
            ull key = (((ull)__float_as_uint(cost_s[i])) << 32) | (unsigned)i;
            if (key < best) best = key;
        }
    }
#pragma unroll
    for (int off = 32; off; off >>= 1) {
        ull o = __shfl_down(best, off, 64);
        if (o < best) best = o;
    }
    if (lane == 0) ctr_s[k] = (best == ~0ull) ? 0 : (int)(best & 0xFFFFFFFFu);
    __syncthreads();
    const float* db = d + (size_t)b * SS * SS;
    if (!last) {
        // next assign for this quarter's 256 tokens; 4 thread-groups each
        // cover 4 clusters; packed-key min => smallest dist, tie smallest k.
        int tok = q * 256 + (tid & 255);
        int g = tid >> 8;
        ull bk = ~0ull;
#pragma unroll
        for (int kk = 0; kk < 4; ++kk) {
            int k2 = g * 4 + kk;
            float vv = db[(size_t)ctr_s[k2] * SS + tok];
            ull key = (((ull)__float_as_uint(vv)) << 32) | (unsigned)k2;
            if (key < bk) bk = key;
        }
        pk[g][tid & 255] = bk;
        __syncthreads();
        if (tid < 256) {
            ull m = pk[0][tid];
            if (pk[1][tid] < m) m = pk[1][tid];
            if (pk[2][tid] < m) m = pk[2][tid];
            if (pk[3][tid] < m) m = pk[3][tid];
            assign[b * SS + q * 256 + tid] = (int)(m & 0xFFFFFFFFu);
        }
    } else {
        // final gather quarter: out[b][f][k] = x[b][f][ctr[k]]
        int e = q * 1024 + tid;     // FF*KK = 4096 elements total
        int f = e / KK, k2 = e % KK;
        out[((size_t)b * FF + f) * KK + k2] = x[((size_t)b * FF + f) * SS + ctr_s[k2]];
    }
}

extern "C" void kernel_launch(void* const* d_in, const int* in_sizes, int n_in,
                              void* d_out, int out_size, void* d_ws, size_t ws_size,
                              hipStream_t stream) {
    const float* x = (const float*)d_in[0];   // [B,F,S]
    const float* w = (const float*)d_in[1];   // [B,S,S]
    float* out = (float*)d_out;               // [B,F,K]

    char* ws = (char*)d_ws;
    float* d = (float*)ws;                              // B*S*S floats = 33.55 MB
    size_t off = (size_t)BB * SS * SS * sizeof(float);
    float* wm = (float*)(ws + off);   off += (size_t)BB * SS * sizeof(float);
    int* assign = (int*)(ws + off);   off += (size_t)BB * SS * sizeof(int);
    float* cost = (float*)(ws + off); off += (size_t)BB * SS * sizeof(float);
    float* part = (float*)(ws + off); // [ICH][B][S] = 256 KB (non-aliasing:
                                      // consumed by topk AFTER dist runs)

    // dist first, wm_part second — independent data; wm_part's 256 blocks
    // backfill dist's ragged drain tail (544 blocks over 256 CUs).
    dist_kernel<<<dim3(68, BB), 128, 0, stream>>>(x, d);
    wm_part_kernel<<<dim3(SS / 256, ICH, BB), 256, 0, stream>>>(w, part);
    topk_assign_kernel<<<BB, 1024, 0, stream>>>(part, wm, d, assign);
    for (int itr = 0; itr < ITERS; ++itr) {
        cost_kernel<<<dim3(SS / RPB, BB), 256, 0, stream>>>(d, wm, assign, cost);
        update_assign_kernel<<<dim3(4, BB), 1024, 0, stream>>>(d, cost, assign, x, out,
                                                               itr == ITERS - 1 ? 1 : 0);
    }
}

// Round 8
// 252.571 us; speedup vs baseline: 4.3017x; 1.1184x over previous
//
#include <hip/hip_runtime.h>
#include <math.h>

#define BB 8
#define FF 256
#define SS 1024
#define KK 16
#define ITERS 5

typedef unsigned long long ull;

// R12 POST-MORTEM: cooperative grid.sync() fusion = 850us for the loop
// (VALUBusy 1.2%, 9 barriers ~= 94us each). Grid-wide software barriers
// are ~10x a kernel-launch boundary on MI355X. Multi-launch it is.
// R10 POST-MORTEM: 64x64 tile per wave = 544 blocks = 1 wave/SIMD ->
// Occupancy 9.2%, VALUBusy 41% (0.71 block-imbalance x 0.6 latency
// exposure), dist 147us. Grid too coarse; LDS efficiency isn't worth
// occupancy on this part.

// ---------- wm stage 1: partial column sums of w ----------
#define ICH 8
__global__ void wm_part_kernel(const float* __restrict__ w, float* __restrict__ part) {
    int j = blockIdx.x * 256 + threadIdx.x;
    int ic = blockIdx.y, b = blockIdx.z;
    const float* wp = w + (size_t)b * SS * SS + (size_t)ic * (SS / ICH) * SS + j;
    float s = 0.f;
#pragma unroll 16
    for (int i = 0; i < SS / ICH; ++i) s += wp[(size_t)i * SS];
    part[((size_t)ic * BB + b) * SS + j] = s;
}

// ---------- d[b][i][j] = sum_f |x[b][f][i] - x[b][f][j]| ----------
// R5: 64x64 tile per BLOCK, 2 waves split rows (32x64, 4x8 acc/lane).
// 1088 blocks (4.25/CU, tail 1.18x) = 2176 waves = 2.1/SIMD -> cross-wave
// latency hiding. Tile shared in LDS (8 KB, double-buffered); raw
// s_barrier (NOT __syncthreads -- that drains vmcnt and kills prefetch):
//   bar#1 (WAR: no wave still reads buf we overwrite) -> stage k+1 ->
//   vmcnt(2) own chunk-k loads -> bar#2 (all waves' loads visible) ->
//   compute chunk k.
// Per-element f order unchanged -> d bitwise identical to R3-verified.
#define FCD 8
#define TS 64
#define NT (SS / TS)
__device__ __forceinline__ void async_copy16(const float* g, const float* s) {
    __builtin_amdgcn_global_load_lds((const __attribute__((address_space(1))) void*)g,
                                     (__attribute__((address_space(3))) void*)s, 16, 0, 0);
}

__global__ __launch_bounds__(128, 4) void dist_kernel(const float* __restrict__ x,
                                                      float* __restrict__ d) {
    __shared__ float smem[2048];   // buf0 [A 512|B 512] | buf1 [A 512|B 512]
    int tid = threadIdx.x;
    int wave = tid >> 6, lane = tid & 63;
    int b = blockIdx.y;
    int w = blockIdx.x;                 // 0..135 triangular tile id (64x64 tiles)
    int it = 0, rem = w;
    while (rem >= NT - it) { rem -= NT - it; ++it; }
    int jt = it + rem;
    int i0 = it * TS, j0 = jt * TS;
    const float* xb = x + (size_t)b * FF * SS;
    float* db = d + (size_t)b * SS * SS;
    // compute mapping: wave w rows w*32 + (lane>>3)*4 + r, cols (lane&7)*8 + c
    int rl = wave * 32 + (lane >> 3) * 4;
    int cl = (lane & 7) * 8;
    // staging mapping: thread tid covers f = tid>>4 (0..7), tok (tid&15)*4
    int sF = tid >> 4, sT = (tid & 15) * 4;

    float acc[4][8] = {};

    auto stage = [&](int c, int h) {
        // LDS dest base must be wave-uniform: wave covers f rows 4w..4w+3
        float* A = smem + h * 1024 + wave * 256;
        const float* base = xb + ((size_t)c * FCD + sF) * SS + sT;
        async_copy16(base + i0, A);          // A: 8f x 64tok (this wave: half)
        async_copy16(base + j0, A + 512);    // B likewise
    };
    auto compute = [&](int h) {
        const float* A = smem + h * 1024;
        const float* B = A + 512;
#pragma unroll
        for (int f = 0; f < FCD; ++f) {
            float4 a4 = *(const float4*)(A + f * 64 + rl);
            float4 b0 = *(const float4*)(B + f * 64 + cl);
            float4 b1 = *(const float4*)(B + f * 64 + cl + 4);
            float av[4] = {a4.x, a4.y, a4.z, a4.w};
            float bv[8] = {b0.x, b0.y, b0.z, b0.w, b1.x, b1.y, b1.z, b1.w};
#pragma unroll
            for (int r = 0; r < 4; ++r)
#pragma unroll
                for (int c = 0; c < 8; ++c)
                    acc[r][c] += fabsf(av[r] - bv[c]);
        }
    };

    stage(0, 0);
#pragma unroll 1
    for (int k = 0; k < FF / FCD - 1; ++k) {
        // bar#1: every wave finished compute(k-1) -> nobody still reads
        // buf[(k+1)&1]; own ds_reads retired before their uses (lgkmcnt).
        asm volatile("s_barrier" ::: "memory");
        stage(k + 1, (k + 1) & 1);
        // own chunk-k loads landed; chunk k+1's 2 stay in flight
        asm volatile("s_waitcnt vmcnt(2)" ::: "memory");
        // bar#2: ALL waves' chunk-k loads landed (each waited before here)
        asm volatile("s_barrier" ::: "memory");
        compute(k & 1);
    }
    asm volatile("s_waitcnt vmcnt(0)" ::: "memory");
    asm volatile("s_barrier" ::: "memory");
    compute(1);   // chunk 31 -> buffer 1

    // direct tile: rows i0+rl+r, cols j0+cl..cl+7
#pragma unroll
    for (int r = 0; r < 4; ++r) {
        float4 v0 = make_float4(acc[r][0], acc[r][1], acc[r][2], acc[r][3]);
        float4 v1 = make_float4(acc[r][4], acc[r][5], acc[r][6], acc[r][7]);
        float* row = &db[(size_t)(i0 + rl + r) * SS + j0 + cl];
        *(float4*)row = v0;
        *(float4*)(row + 4) = v1;
    }
    if (it != jt) {
        // mirror straight from registers (d bitwise symmetric)
#pragma unroll
        for (int c = 0; c < 8; ++c) {
            float4 v = make_float4(acc[0][c], acc[1][c], acc[2][c], acc[3][c]);
            *(float4*)&db[(size_t)(j0 + cl + c) * SS + i0 + rl] = v;
        }
    }
}

// ---------- wm finalize + topk (jax.lax.top_k) + initial assign, fused ----------
// wm > 0 strictly (means of uniform[0,1)), so float bits are order-monotonic.
__global__ __launch_bounds__(1024) void topk_assign_kernel(const float* __restrict__ part,
                                                           float* __restrict__ wm,
                                                           const float* __restrict__ d,
                                                           int* __restrict__ assign) {
    int b = blockIdx.x;
    int tid = threadIdx.x;          // == token index
    int lane = tid & 63, wv = tid >> 6;
    __shared__ ull red[16];
    __shared__ int ctr_s[KK];
    // finalize wm for this batch (same ascending-ic order as before)
    float v = 0.f;
#pragma unroll
    for (int ic = 0; ic < ICH; ++ic) v += part[((size_t)ic * BB + b) * SS + tid];
    v *= (1.0f / SS);
    wm[b * SS + tid] = v;
    // key: value-desc, tie -> smaller index (complemented idx, max-reduce)
    ull key = (((ull)__float_as_uint(v)) << 32) | (ull)(0xFFFFFFFFu - (unsigned)tid);
    for (int k = 0; k < KK; ++k) {
        ull kk = key;
#pragma unroll
        for (int off = 32; off; off >>= 1) {
            ull o = __shfl_down(kk, off, 64);
            if (o > kk) kk = o;
        }
        if (lane == 0) red[wv] = kk;
        __syncthreads();
        if (wv == 0) {
            ull k2 = (lane < 16) ? red[lane] : 0ull;
#pragma unroll
            for (int off = 8; off; off >>= 1) {
                ull o = __shfl_down(k2, off, 64);
                if (o > k2) k2 = o;
            }
            if (lane == 0) red[0] = k2;
        }
        __syncthreads();
        ull W = red[0];
        int widx = (int)(0xFFFFFFFFu - (unsigned)(W & 0xFFFFFFFFu));
        if (tid == widx) key = 0;            // remove winner
        if (tid == 0) ctr_s[k] = widx;
        __syncthreads();                      // protect red[] before next round
    }
    // initial assign: argmin_k d[ctr[k]][i] (d symmetric; coalesced over i)
    const float* db = d + (size_t)b * SS * SS;
    float bv = INFINITY;
    int bk = 0;
#pragma unroll
    for (int k = 0; k < KK; ++k) {
        float vv = db[(size_t)ctr_s[k] * SS + tid];
        if (vv < bv) { bv = vv; bk = k; }    // strict < keeps first k
    }
    assign[b * SS + tid] = bk;
}

// ---------- cost[b][i] = sum_{j: assign[j]==assign[i]} d[i][j]*wm[j] ----------
// 16 rows per block: wm+assign cached in LDS once, 4 waves x 4 rows,
// barrier-free per-row wave reduction.
#define RPB 16
__global__ __launch_bounds__(256) void cost_kernel(const float* __restrict__ d,
                                                   const float* __restrict__ wm,
                                                   const int* __restrict__ assign,
                                                   float* __restrict__ cost) {
    int b = blockIdx.y;
    int tid = threadIdx.x;
    int lane = tid & 63, wv = tid >> 6;
    __shared__ float wmv[SS];
    __shared__ int asg[SS];
    *(float4*)&wmv[tid * 4] = *(const float4*)&wm[b * SS + tid * 4];
    *(int4*)&asg[tid * 4] = *(const int4*)&assign[b * SS + tid * 4];
    __syncthreads();
    const float* db = d + (size_t)b * SS * SS;
#pragma unroll
    for (int r = 0; r < RPB / 4; ++r) {
        int i = blockIdx.x * RPB + wv * (RPB / 4) + r;
        int my = asg[i];
        const float* drow = db + (size_t)i * SS;
        float s = 0.f;
#pragma unroll
        for (int c = 0; c < SS / 256; ++c) {      // 4 sweeps of 64 lanes x float4
            int j = c * 256 + lane * 4;
            float4 dv = *(const float4*)&drow[j];
            float4 wv4 = *(const float4*)&wmv[j];
            int4 a4 = *(const int4*)&asg[j];
            s += (a4.x == my) ? dv.x * wv4.x : 0.f;
            s += (a4.y == my) ? dv.y * wv4.y : 0.f;
            s += (a4.z == my) ? dv.z * wv4.z : 0.f;
            s += (a4.w == my) ? dv.w * wv4.w : 0.f;
        }
#pragma unroll
        for (int off = 32; off; off >>= 1) s += __shfl_down(s, off, 64);
        if (lane == 0) cost[b * SS + i] = s;
    }
}

// ---------- medoid update (+ next assign, or final gather), widened ----------
// grid (4, B): each block redundantly computes all K medoids (cheap 8 KB
// LDS scan), then handles a 256-token quarter of the assign (or gather).
__global__ __launch_bounds__(1024) void update_assign_kernel(
        const float* __restrict__ d, const float* __restrict__ cost,
        int* __restrict__ assign, const float* __restrict__ x,
        float* __restrict__ out, int last) {
    int b = blockIdx.y;
    int q = blockIdx.x;             // quarter 0..3
    int tid = threadIdx.x;
    int lane = tid & 63, wv = tid >> 6;
    __shared__ float cost_s[SS];
    __shared__ int assign_s[SS];
    __shared__ int ctr_s[KK];
    __shared__ ull pk[4][256];
    cost_s[tid] = cost[b * SS + tid];
    assign_s[tid] = assign[b * SS + tid];
    __syncthreads();
    // per-cluster argmin: wave wv handles cluster k=wv.
    // cost >= 0 finite, so float bits are order-monotonic.
    ull best = ~0ull;
    int k = wv;   // 16 waves, 16 clusters
    for (int c = 0; c < SS / 64; ++c) {
        int i = c * 64 + lane;
        if (assign_s[i] == k) {
            ull key = (((ull)__float_as_uint(cost_s[i])) << 32) | (unsigned)i;
            if (key < best) best = key;
        }
    }
#pragma unroll
    for (int off = 32; off; off >>= 1) {
        ull o = __shfl_down(best, off, 64);
        if (o < best) best = o;
    }
    if (lane == 0) ctr_s[k] = (best == ~0ull) ? 0 : (int)(best & 0xFFFFFFFFu);
    __syncthreads();
    const float* db = d + (size_t)b * SS * SS;
    if (!last) {
        // next assign for this quarter's 256 tokens; 4 thread-groups each
        // cover 4 clusters; packed-key min => smallest dist, tie smallest k.
        int tok = q * 256 + (tid & 255);
        int g = tid >> 8;
        ull bk = ~0ull;
#pragma unroll
        for (int kk = 0; kk < 4; ++kk) {
            int k2 = g * 4 + kk;
            float vv = db[(size_t)ctr_s[k2] * SS + tok];
            ull key = (((ull)__float_as_uint(vv)) << 32) | (unsigned)k2;
            if (key < bk) bk = key;
        }
        pk[g][tid & 255] = bk;
        __syncthreads();
        if (tid < 256) {
            ull m = pk[0][tid];
            if (pk[1][tid] < m) m = pk[1][tid];
            if (pk[2][tid] < m) m = pk[2][tid];
            if (pk[3][tid] < m) m = pk[3][tid];
            assign[b * SS + q * 256 + tid] = (int)(m & 0xFFFFFFFFu);
        }
    } else {
        // final gather quarter: out[b][f][k] = x[b][f][ctr[k]]
        int e = q * 1024 + tid;     // FF*KK = 4096 elements total
        int f = e / KK, k2 = e % KK;
        out[((size_t)b * FF + f) * KK + k2] = x[((size_t)b * FF + f) * SS + ctr_s[k2]];
    }
}

extern "C" void kernel_launch(void* const* d_in, const int* in_sizes, int n_in,
                              void* d_out, int out_size, void* d_ws, size_t ws_size,
                              hipStream_t stream) {
    const float* x = (const float*)d_in[0];   // [B,F,S]
    const float* w = (const float*)d_in[1];   // [B,S,S]
    float* out = (float*)d_out;               // [B,F,K]

    char* ws = (char*)d_ws;
    float* d = (float*)ws;                              // B*S*S floats = 33.55 MB
    size_t off = (size_t)BB * SS * SS * sizeof(float);
    float* wm = (float*)(ws + off);   off += (size_t)BB * SS * sizeof(float);
    int* assign = (int*)(ws + off);   off += (size_t)BB * SS * sizeof(int);
    float* cost = (float*)(ws + off); off += (size_t)BB * SS * sizeof(float);
    float* part = (float*)(ws + off); // [ICH][B][S] = 256 KB (non-aliasing:
                                      // consumed by topk AFTER dist runs)

    // dist first, wm_part second — independent data; wm_part's 256 blocks
    // backfill dist's ragged drain tail.
    // 136 triangular 64x64 tiles per batch, one tile per 128-thread block.
    dist_kernel<<<dim3(136, BB), 128, 0, stream>>>(x, d);
    wm_part_kernel<<<dim3(SS / 256, ICH, BB), 256, 0, stream>>>(w, part);
    topk_assign_kernel<<<BB, 1024, 0, stream>>>(part, wm, d, assign);
    for (int itr = 0; itr < ITERS; ++itr) {
        cost_kernel<<<dim3(SS / RPB, BB), 256, 0, stream>>>(d, wm, assign, cost);
        update_assign_kernel<<<dim3(4, BB), 1024, 0, stream>>>(d, cost, assign, x, out,
                                                               itr == ITERS - 1 ? 1 : 0);
    }
}